// Round 7
// baseline (1715.199 us; speedup 1.0000x reference)
//
#include <hip/hip_runtime.h>
#include <math.h>

#define HH  64
#define TT  2048
#define IND 7
#define NT  512

typedef float f4 __attribute__((ext_vector_type(4)));

__device__ __forceinline__ f4 fma4(f4 a, f4 b, f4 c) {
    return __builtin_elementwise_fma(a, b, c);
}

template <int CTRL>
__device__ __forceinline__ float qperm(float x) {
    return __int_as_float(__builtin_amdgcn_update_dpp(0, __float_as_int(x), CTRL, 0xf, 0xf, true));
}
#define QP_X1 0xB1  // quad_perm(1,0,3,2)
#define QP_X2 0x4E  // quad_perm(2,3,0,1)
#define QP_X3 0x1B  // quad_perm(3,2,1,0)

// gate activation; tanh sector's pre-activation is pre-scaled by 2 via weights
__device__ __forceinline__ float gact(float a, bool is_t) {
    float e  = __expf(-a);
    float sg = __fdividef(1.0f, 1.0f + e);
    return is_t ? fmaf(2.0f, sg, -1.0f) : sg;
}
__device__ __forceinline__ float tanh_s(float c) {
    float e = __expf(-2.0f * c);
    return fmaf(2.0f, __fdividef(1.0f, 1.0f + e), -1.0f);
}

__global__ __launch_bounds__(NT) __attribute__((amdgpu_waves_per_eu(2, 2)))
void lstm2_fused(
    const float* __restrict__ x,     // (B,7,2048)
    const float* __restrict__ Wih0,  // (256,7)
    const float* __restrict__ Whh0,  // (256,64)
    const float* __restrict__ bih0, const float* __restrict__ bhh0,
    const float* __restrict__ Wih1,  // (256,64)
    const float* __restrict__ Whh1,  // (256,64)
    const float* __restrict__ bih1, const float* __restrict__ bhh1,
    const float* __restrict__ W1,    // (10,64)
    const float* __restrict__ b1v,   // (10)
    const float* __restrict__ gmma, const float* __restrict__ beta,
    const float* __restrict__ rm,   const float* __restrict__ rv,
    const float* __restrict__ W2,   // (1,10)
    const float* __restrict__ b2,   // (1)
    float* __restrict__ out)         // (B,1)
{
    const int b    = blockIdx.x;
    const int tid  = threadIdx.x;
    const int grp  = tid >> 8;          // 0: layer-0 waves(0-3), 1: layer-1 waves(4-7)
    const int tg   = tid & 255;
    const int s    = tg & 3;            // gate 0:i 1:f 2:g 3:o (quad-local)
    const int j    = tg >> 2;           // hidden unit 0..63
    const int g    = (s << 6) | j;      // gate row

    __shared__ __align__(16) float xT[TT][8];     // 64 KB, xT[t][0..6], [7]=0 pad
    __shared__ __align__(16) float h0s[2][HH];
    __shared__ __align__(16) float h1s[2][HH];
    __shared__ float yv[10];

    // ---- stage x[b] transposed ----
    {
        const float* xg = x + (size_t)b * (IND * TT);
        for (int i = tid; i < IND * TT; i += NT) {
            int d = i >> 11;
            int t = i & (TT - 1);
            xT[t][d] = xg[i];
        }
        for (int t = tid; t < TT; t += NT) xT[t][7] = 0.0f;
        if (tid < HH) { h0s[1][tid] = 0.0f; h1s[0][tid] = 0.0f; h1s[1][tid] = 0.0f; }
    }

    const float sc   = (s == 2) ? 2.0f : 1.0f;   // exact pow2 pre-scale for tanh gate
    const bool  is_t = (s == 2);
    const bool  a1b  = (s & 1) != 0;
    const bool  a2b  = (s & 2) != 0;

    __syncthreads();

    if (grp == 0) {
        // ============ LAYER-0 GROUP: computes h0(tick) at tick ============
        f4 w[16];
        {
            const f4* pw = (const f4*)(Whh0 + g * HH);
            #pragma unroll
            for (int r = 0; r < 16; ++r) w[r] = pw[r] * sc;
        }
        f4 xwa, xwb;
        xwa.x = Wih0[g*IND+0]; xwa.y = Wih0[g*IND+1]; xwa.z = Wih0[g*IND+2]; xwa.w = Wih0[g*IND+3];
        xwb.x = Wih0[g*IND+4]; xwb.y = Wih0[g*IND+5]; xwb.z = Wih0[g*IND+6]; xwb.w = 0.0f;
        xwa *= sc; xwb *= sc;
        const float bg = (bih0[g] + bhh0[g]) * sc;

        float c0 = 0.0f;
        f4 xqa = *((const f4*)&xT[0][0]);
        f4 xqb = *((const f4*)&xT[0][4]);

        for (int tick = 0; tick <= TT; ++tick) {
            const int p = tick & 1;
            if (tick < TT) {
                const f4* hp = (const f4*)&h0s[p ^ 1][0];   // wave-uniform broadcast
                f4 A0; A0.x = bg; A0.y = 0.f; A0.z = 0.f; A0.w = 0.f;
                f4 A1 = (f4)(0.0f), A2 = (f4)(0.0f), A3 = (f4)(0.0f);
                #pragma unroll
                for (int r = 0; r < 4; ++r) {
                    A0 = fma4(w[4*r+0], hp[4*r+0], A0);
                    A1 = fma4(w[4*r+1], hp[4*r+1], A1);
                    A2 = fma4(w[4*r+2], hp[4*r+2], A2);
                    A3 = fma4(w[4*r+3], hp[4*r+3], A3);
                }
                A0 = fma4(xwa, xqa, A0);
                A1 = fma4(xwb, xqb, A1);
                f4 am = (A0 + A1) + (A2 + A3);
                float a = (am.x + am.y) + (am.z + am.w);
                float act = gact(a, is_t);
                // quad gather: gate t of this unit sits at lane s^t
                float x1 = qperm<QP_X1>(act);
                float x2 = qperm<QP_X2>(act);
                float x3 = qperm<QP_X3>(act);
                float p02 = act * x2, p13 = x1 * x3;
                float ig = a1b ? p13 : p02;                 // i*g
                float t1 = a2b ? x2 : act, t2 = a2b ? x3 : x1;
                float fv = a1b ? t1 : t2;                   // f
                float o1 = a2b ? act : x2, o2 = a2b ? x1 : x3;
                float ov = a1b ? o1 : o2;                   // o
                c0 = fmaf(fv, c0, ig);
                float hn = ov * tanh_s(c0);
                if (s == 0) h0s[p][j] = hn;
                const int tn = (tick + 1) & (TT - 1);
                xqa = *((const f4*)&xT[tn][0]);
                xqb = *((const f4*)&xT[tn][4]);
            }
            __syncthreads();
        }
    } else {
        // ====== LAYER-1 GROUP: computes h1(tick-1) at tick (one behind) ======
        f4 wi[16], wh[16];
        {
            const f4* pa = (const f4*)(Wih1 + g * HH);
            const f4* pb = (const f4*)(Whh1 + g * HH);
            #pragma unroll
            for (int r = 0; r < 16; ++r) { wi[r] = pa[r] * sc; wh[r] = pb[r] * sc; }
        }
        const float bg = (bih1[g] + bhh1[g]) * sc;

        float c1 = 0.0f;

        for (int tick = 0; tick <= TT; ++tick) {
            const int p = tick & 1;
            if (tick > 0) {
                const f4* hp0 = (const f4*)&h0s[p ^ 1][0];  // h0(tick-1)
                const f4* hp1 = (const f4*)&h1s[p ^ 1][0];  // h1(tick-2)
                f4 A0; A0.x = bg; A0.y = 0.f; A0.z = 0.f; A0.w = 0.f;
                f4 A1 = (f4)(0.0f), A2 = (f4)(0.0f), A3 = (f4)(0.0f);
                #pragma unroll
                for (int r = 0; r < 4; ++r) {
                    A0 = fma4(wi[4*r+0], hp0[4*r+0], A0);
                    A1 = fma4(wi[4*r+1], hp0[4*r+1], A1);
                    A2 = fma4(wi[4*r+2], hp0[4*r+2], A2);
                    A3 = fma4(wi[4*r+3], hp0[4*r+3], A3);
                }
                #pragma unroll
                for (int r = 0; r < 4; ++r) {
                    A0 = fma4(wh[4*r+0], hp1[4*r+0], A0);
                    A1 = fma4(wh[4*r+1], hp1[4*r+1], A1);
                    A2 = fma4(wh[4*r+2], hp1[4*r+2], A2);
                    A3 = fma4(wh[4*r+3], hp1[4*r+3], A3);
                }
                f4 am = (A0 + A1) + (A2 + A3);
                float a = (am.x + am.y) + (am.z + am.w);
                float act = gact(a, is_t);
                float x1 = qperm<QP_X1>(act);
                float x2 = qperm<QP_X2>(act);
                float x3 = qperm<QP_X3>(act);
                float p02 = act * x2, p13 = x1 * x3;
                float ig = a1b ? p13 : p02;
                float t1 = a2b ? x2 : act, t2 = a2b ? x3 : x1;
                float fv = a1b ? t1 : t2;
                float o1 = a2b ? act : x2, o2 = a2b ? x1 : x3;
                float ov = a1b ? o1 : o2;
                c1 = fmaf(fv, c1, ig);
                float hn = ov * tanh_s(c1);
                if (s == 0) h1s[p][j] = hn;
            }
            __syncthreads();
        }
    }

    // h1(TT-1) was stored at tick TT into h1s[TT&1] = h1s[0]
    if (tid < 10) {
        float y = b1v[tid];
        #pragma unroll
        for (int k = 0; k < HH; ++k) y += W1[tid * HH + k] * h1s[0][k];
        y = (y - rm[tid]) * rsqrtf(rv[tid] + 1e-5f) * gmma[tid] + beta[tid];
        y = fmaxf(y, 0.0f);
        yv[tid] = y * W2[tid];
    }
    __syncthreads();
    if (tid == 0) {
        float sacc = b2[0];
        #pragma unroll
        for (int k = 0; k < 10; ++k) sacc += yv[k];
        out[b] = sacc;
    }
}

extern "C" void kernel_launch(void* const* d_in, const int* in_sizes, int n_in,
                              void* d_out, int out_size, void* d_ws, size_t ws_size,
                              hipStream_t stream) {
    const float* x    = (const float*)d_in[0];
    const float* Wih0 = (const float*)d_in[1];
    const float* Whh0 = (const float*)d_in[2];
    const float* bih0 = (const float*)d_in[3];
    const float* bhh0 = (const float*)d_in[4];
    const float* Wih1 = (const float*)d_in[5];
    const float* Whh1 = (const float*)d_in[6];
    const float* bih1 = (const float*)d_in[7];
    const float* bhh1 = (const float*)d_in[8];
    const float* W1   = (const float*)d_in[9];
    const float* b1   = (const float*)d_in[10];
    const float* gmma = (const float*)d_in[11];
    const float* beta = (const float*)d_in[12];
    const float* rm   = (const float*)d_in[13];
    const float* rv   = (const float*)d_in[14];
    const float* W2   = (const float*)d_in[15];
    const float* b2   = (const float*)d_in[16];

    const int B = in_sizes[0] / (IND * TT);   // 256

    lstm2_fused<<<dim3(B), dim3(NT), 0, stream>>>(
        x, Wih0, Whh0, bih0, bhh0, Wih1, Whh1, bih1, bhh1,
        W1, b1, gmma, beta, rm, rv, W2, b2, (float*)d_out);
}